// Round 1
// baseline (2279.992 us; speedup 1.0000x reference)
//
#include <hip/hip_runtime.h>

#define BDIM 8
#define LDIM 2048
#define DDIM 1024
#define NL 3
#define K4 4
#define MDIM (BDIM * LDIM) /* 16384 rows */

typedef __bf16 bf16x8 __attribute__((ext_vector_type(8)));
typedef __bf16 bf16x4 __attribute__((ext_vector_type(4)));
typedef float f32x4 __attribute__((ext_vector_type(4)));

__global__ void cvt_bf16(const float* __restrict__ s, __bf16* __restrict__ d, int n) {
    int i = blockIdx.x * 256 + threadIdx.x;
    if (i < n) d[i] = (__bf16)s[i];
}

// causal depthwise conv1d, kernel 4, left pad 3.  X:(B,L,D) -> XC:(B,L,D)
__global__ void conv_kernel(const float* __restrict__ X, const float* __restrict__ cw,
                            const float* __restrict__ cb, float* __restrict__ XC) {
    int idx = blockIdx.x * 256 + threadIdx.x;
    int d = idx & (DDIM - 1);
    int t = (idx >> 10) & (LDIM - 1);
    int b = idx >> 21;
    float acc = cb[d];
    const float* cwd = cw + d * K4;
#pragma unroll
    for (int k = 0; k < K4; k++) {
        int tt = t + k - (K4 - 1);
        if (tt >= 0) acc += X[((size_t)(b * LDIM + tt) << 10) + d] * cwd[k];
    }
    XC[idx] = acc;
}

// Dual GEMM: r = A @ Wr^T + wrb, i = A @ Wi^T + wib  (A: M x K fp32, W: N x K bf16)
// epilogue: loga = 8*sigmoid(r)*ln(sigmoid(la));  bb = sqrt(max(1-a^2,1e-6))*sigmoid(i)*A
__global__ __launch_bounds__(256) void dual_gemm_gate(
    const float* __restrict__ A, const __bf16* __restrict__ Wr, const __bf16* __restrict__ Wi,
    const float* __restrict__ wrb, const float* __restrict__ wib, const float* __restrict__ la,
    float* __restrict__ LOGA, float* __restrict__ BB) {
    const int K = DDIM;
    __shared__ __bf16 As[128][32];
    __shared__ __bf16 Bs[2][128][32];
    int tid = threadIdx.x;
    int bm0 = blockIdx.y * 128, bn0 = blockIdx.x * 128;
    int wave = tid >> 6, lane = tid & 63;
    int wm = (wave >> 1) * 64, wn = (wave & 1) * 64;
    int fr = lane & 15, quad = lane >> 4;
    f32x4 accr[4][4], acci[4][4];
    f32x4 zero = {0.f, 0.f, 0.f, 0.f};
#pragma unroll
    for (int i = 0; i < 4; i++)
#pragma unroll
        for (int j = 0; j < 4; j++) { accr[i][j] = zero; acci[i][j] = zero; }

    for (int ko = 0; ko < K; ko += 32) {
        __syncthreads();
        // A tile: 128x32 fp32 -> bf16 LDS (1024 float4 loads, 4 per thread, coalesced)
#pragma unroll
        for (int i = tid; i < 1024; i += 256) {
            int r = i >> 3, kc = (i & 7) << 2;
            float4 v = *(const float4*)(A + (size_t)(bm0 + r) * K + ko + kc);
            bf16x4 t;
            t.x = (__bf16)v.x; t.y = (__bf16)v.y; t.z = (__bf16)v.z; t.w = (__bf16)v.w;
            *(bf16x4*)&As[r][kc] = t;
        }
        // B tiles (already bf16): 128x32 each, 16B chunks
#pragma unroll
        for (int i = tid; i < 512; i += 256) {
            int r = i >> 2, kc = (i & 3) << 3;
            *(bf16x8*)&Bs[0][r][kc] = *(const bf16x8*)(Wr + (size_t)(bn0 + r) * K + ko + kc);
            *(bf16x8*)&Bs[1][r][kc] = *(const bf16x8*)(Wi + (size_t)(bn0 + r) * K + ko + kc);
        }
        __syncthreads();
        bf16x8 af[4];
#pragma unroll
        for (int mi = 0; mi < 4; mi++) af[mi] = *(bf16x8*)&As[wm + mi * 16 + fr][quad * 8];
#pragma unroll
        for (int ni = 0; ni < 4; ni++) {
            bf16x8 br = *(bf16x8*)&Bs[0][wn + ni * 16 + fr][quad * 8];
            bf16x8 bi = *(bf16x8*)&Bs[1][wn + ni * 16 + fr][quad * 8];
#pragma unroll
            for (int mi = 0; mi < 4; mi++) {
                accr[mi][ni] = __builtin_amdgcn_mfma_f32_16x16x32_bf16(af[mi], br, accr[mi][ni], 0, 0, 0);
                acci[mi][ni] = __builtin_amdgcn_mfma_f32_16x16x32_bf16(af[mi], bi, acci[mi][ni], 0, 0, 0);
            }
        }
    }
#pragma unroll
    for (int ni = 0; ni < 4; ni++) {
        int n = bn0 + wn + ni * 16 + fr;
        float lav = la[n];
        float ab = 1.f / (1.f + expf(-lav));
        float lnab = logf(ab);
        float br_ = wrb[n], bi_ = wib[n];
#pragma unroll
        for (int mi = 0; mi < 4; mi++) {
#pragma unroll
            for (int reg = 0; reg < 4; reg++) {
                int m = bm0 + wm + mi * 16 + quad * 4 + reg;
                float rl = accr[mi][ni][reg] + br_;
                float il = acci[mi][ni][reg] + bi_;
                float r = 1.f / (1.f + expf(-rl));
                float iv = 1.f / (1.f + expf(-il));
                float lga = 8.f * r * lnab;
                float a = expf(lga);
                float xc = A[(size_t)m * DDIM + n];
                float bt = sqrtf(fmaxf(1.f - a * a, 1e-6f)) * (iv * xc);
                size_t off = (size_t)m * DDIM + n;
                LOGA[off] = lga;
                BB[off] = bt;
            }
        }
    }
}

// Plain GEMM: HW = A @ Wo^T
__global__ __launch_bounds__(256) void out_gemm(
    const float* __restrict__ A, const __bf16* __restrict__ Wo, float* __restrict__ HW) {
    const int K = DDIM;
    __shared__ __bf16 As[128][32];
    __shared__ __bf16 Bs[128][32];
    int tid = threadIdx.x;
    int bm0 = blockIdx.y * 128, bn0 = blockIdx.x * 128;
    int wave = tid >> 6, lane = tid & 63;
    int wm = (wave >> 1) * 64, wn = (wave & 1) * 64;
    int fr = lane & 15, quad = lane >> 4;
    f32x4 acc[4][4];
    f32x4 zero = {0.f, 0.f, 0.f, 0.f};
#pragma unroll
    for (int i = 0; i < 4; i++)
#pragma unroll
        for (int j = 0; j < 4; j++) acc[i][j] = zero;

    for (int ko = 0; ko < K; ko += 32) {
        __syncthreads();
#pragma unroll
        for (int i = tid; i < 1024; i += 256) {
            int r = i >> 3, kc = (i & 7) << 2;
            float4 v = *(const float4*)(A + (size_t)(bm0 + r) * K + ko + kc);
            bf16x4 t;
            t.x = (__bf16)v.x; t.y = (__bf16)v.y; t.z = (__bf16)v.z; t.w = (__bf16)v.w;
            *(bf16x4*)&As[r][kc] = t;
        }
#pragma unroll
        for (int i = tid; i < 512; i += 256) {
            int r = i >> 2, kc = (i & 3) << 3;
            *(bf16x8*)&Bs[r][kc] = *(const bf16x8*)(Wo + (size_t)(bn0 + r) * K + ko + kc);
        }
        __syncthreads();
        bf16x8 af[4];
#pragma unroll
        for (int mi = 0; mi < 4; mi++) af[mi] = *(bf16x8*)&As[wm + mi * 16 + fr][quad * 8];
#pragma unroll
        for (int ni = 0; ni < 4; ni++) {
            bf16x8 bb = *(bf16x8*)&Bs[wn + ni * 16 + fr][quad * 8];
#pragma unroll
            for (int mi = 0; mi < 4; mi++)
                acc[mi][ni] = __builtin_amdgcn_mfma_f32_16x16x32_bf16(af[mi], bb, acc[mi][ni], 0, 0, 0);
        }
    }
#pragma unroll
    for (int ni = 0; ni < 4; ni++) {
        int n = bn0 + wn + ni * 16 + fr;
#pragma unroll
        for (int mi = 0; mi < 4; mi++) {
#pragma unroll
            for (int reg = 0; reg < 4; reg++) {
                int m = bm0 + wm + mi * 16 + quad * 4 + reg;
                HW[(size_t)m * DDIM + n] = acc[mi][ni][reg];
            }
        }
    }
}

// Clamped log-space linear scan, matching reference semantics:
//   L_t = cumsum(loga); Lc = max(L,-80); h_t = exp(Lc_t - Lc_{t-1}) * h_{t-1} + b_t
// block: (b, 64-d tile); 256 threads = 64 d-lanes x 4 t-chunks of 512.
__global__ __launch_bounds__(256) void scan_kernel(const float* __restrict__ LOGA,
                                                   const float* __restrict__ BB,
                                                   float* __restrict__ H) {
    const int TC = LDIM / 4; // 512
    int b = blockIdx.y;
    int d = blockIdx.x * 64 + (threadIdx.x & 63);
    int c = threadIdx.x >> 6;
    int tbase = c * TC;
    const float* pga = LOGA + ((size_t)b * LDIM) * DDIM + d;
    const float* pbb = BB + ((size_t)b * LDIM) * DDIM + d;
    float* pH = H + ((size_t)b * LDIM) * DDIM + d;

    // phase A: chunk sums of loga
    float S = 0.f;
    for (int t = 0; t < TC; t++) S += pga[(size_t)(tbase + t) * DDIM];
    __shared__ float sS[4][64];
    sS[c][threadIdx.x & 63] = S;
    __syncthreads();
    float L0 = 0.f;
    for (int cc = 0; cc < c; cc++) L0 += sS[cc][threadIdx.x & 63];

    // phase B: chunk (A_c, B_c) with zero input; A_c telescopes from boundaries
    float Lr = L0, lcp = fmaxf(L0, -80.f), hB = 0.f;
    for (int t = 0; t < TC; t++) {
        float lga = pga[(size_t)(tbase + t) * DDIM];
        Lr += lga;
        float lc = fmaxf(Lr, -80.f);
        float al = expf(lc - lcp);
        lcp = lc;
        hB = al * hB + pbb[(size_t)(tbase + t) * DDIM];
    }
    float Ac = expf(fmaxf(Lr, -80.f) - fmaxf(L0, -80.f));
    __shared__ float sA[4][64], sB[4][64];
    sA[c][threadIdx.x & 63] = Ac;
    sB[c][threadIdx.x & 63] = hB;
    __syncthreads();
    float hin = 0.f;
    for (int cc = 0; cc < c; cc++) hin = sA[cc][threadIdx.x & 63] * hin + sB[cc][threadIdx.x & 63];

    // phase C: replay with real h_in, write h
    Lr = L0;
    lcp = fmaxf(L0, -80.f);
    float h = hin;
    for (int t = 0; t < TC; t++) {
        float lga = pga[(size_t)(tbase + t) * DDIM];
        Lr += lga;
        float lc = fmaxf(Lr, -80.f);
        float al = expf(lc - lcp);
        lcp = lc;
        h = al * h + pbb[(size_t)(tbase + t) * DDIM];
        pH[(size_t)(tbase + t) * DDIM] = h;
    }
}

// rmsnorm over last dim (1024); one block per row, 256 threads x float4
__global__ __launch_bounds__(256) void rmsnorm_kernel(const float* __restrict__ X,
                                                      const float* __restrict__ w,
                                                      float* __restrict__ Y) {
    int row = blockIdx.x;
    int tid = threadIdx.x;
    const float4* px = (const float4*)(X + (size_t)row * DDIM);
    float4 v = px[tid];
    float s = v.x * v.x + v.y * v.y + v.z * v.z + v.w * v.w;
#pragma unroll
    for (int o = 32; o > 0; o >>= 1) s += __shfl_down(s, o);
    __shared__ float sw[4];
    if ((tid & 63) == 0) sw[tid >> 6] = s;
    __syncthreads();
    float tot = sw[0] + sw[1] + sw[2] + sw[3];
    float scale = rsqrtf(tot * (1.f / (float)DDIM) + 1e-6f);
    float4 wv = ((const float4*)w)[tid];
    float4 o;
    o.x = v.x * wv.x * scale;
    o.y = v.y * wv.y * scale;
    o.z = v.z * wv.z * scale;
    o.w = v.w * wv.w * scale;
    ((float4*)(Y + (size_t)row * DDIM))[tid] = o;
}

extern "C" void kernel_launch(void* const* d_in, const int* in_sizes, int n_in,
                              void* d_out, int out_size, void* d_ws, size_t ws_size,
                              hipStream_t stream) {
    const float* x = (const float*)d_in[0];
    const float* conv_w = (const float*)d_in[1];
    const float* conv_b = (const float*)d_in[2];
    const float* wr_w = (const float*)d_in[3];
    const float* wr_b = (const float*)d_in[4];
    const float* wi_w = (const float*)d_in[5];
    const float* wi_b = (const float*)d_in[6];
    const float* log_a = (const float*)d_in[7];
    const float* wo_w = (const float*)d_in[8];
    const float* norm_w = (const float*)d_in[9];
    const float* norm_out_w = (const float*)d_in[10];

    char* ws = (char*)d_ws;
    const size_t WSZ = (size_t)NL * DDIM * DDIM; // elements per weight tensor
    __bf16* wr16 = (__bf16*)ws;
    __bf16* wi16 = wr16 + WSZ;
    __bf16* wo16 = wi16 + WSZ;
    float* bufA = (float*)(ws + 3 * WSZ * sizeof(__bf16));
    float* bufB = bufA + (size_t)MDIM * DDIM;
    float* bufC = bufB + (size_t)MDIM * DDIM;

    int ncvt = (int)WSZ;
    cvt_bf16<<<(ncvt + 255) / 256, 256, 0, stream>>>(wr_w, wr16, ncvt);
    cvt_bf16<<<(ncvt + 255) / 256, 256, 0, stream>>>(wi_w, wi16, ncvt);
    cvt_bf16<<<(ncvt + 255) / 256, 256, 0, stream>>>(wo_w, wo16, ncvt);

    const float* P = x;
    for (int l = 0; l < NL; l++) {
        conv_kernel<<<(MDIM * DDIM) / 256, 256, 0, stream>>>(
            P, conv_w + (size_t)l * DDIM * K4, conv_b + (size_t)l * DDIM, bufA);
        dual_gemm_gate<<<dim3(DDIM / 128, MDIM / 128), 256, 0, stream>>>(
            bufA, wr16 + (size_t)l * DDIM * DDIM, wi16 + (size_t)l * DDIM * DDIM,
            wr_b + (size_t)l * DDIM, wi_b + (size_t)l * DDIM, log_a + (size_t)l * DDIM,
            bufB, bufC);
        scan_kernel<<<dim3(DDIM / 64, BDIM), 256, 0, stream>>>(bufB, bufC, bufA);
        out_gemm<<<dim3(DDIM / 128, MDIM / 128), 256, 0, stream>>>(
            bufA, wo16 + (size_t)l * DDIM * DDIM, bufB);
        rmsnorm_kernel<<<MDIM, 256, 0, stream>>>(bufB, norm_w + (size_t)l * DDIM, bufC);
        P = bufC;
    }
    rmsnorm_kernel<<<MDIM, 256, 0, stream>>>(bufC, norm_out_w, (float*)d_out);
}

// Round 3
// 1341.288 us; speedup vs baseline: 1.6999x; 1.6999x over previous
//
#include <hip/hip_runtime.h>

#define BDIM 8
#define LDIM 2048
#define DDIM 1024
#define NL 3
#define K4 4
#define MDIM (BDIM * LDIM) /* 16384 rows */

typedef __bf16 bf16x8 __attribute__((ext_vector_type(8)));
typedef __bf16 bf16x4 __attribute__((ext_vector_type(4)));
typedef float f32x4 __attribute__((ext_vector_type(4)));
typedef const __attribute__((address_space(1))) void gvoid_t;
typedef __attribute__((address_space(3))) void svoid_t;

// HW semantics: wave-uniform LDS base; lane l's 16B lands at base + l*16.
// lds MUST be wave-uniform (m104/m108).
__device__ __forceinline__ void load16(const void* g, void* lds_uniform) {
    __builtin_amdgcn_global_load_lds((gvoid_t*)g, (svoid_t*)lds_uniform, 16, 0, 0);
}

__global__ void cvt_bf16(const float* __restrict__ s, __bf16* __restrict__ d, int n) {
    int i = blockIdx.x * 256 + threadIdx.x;
    if (i < n) d[i] = (__bf16)s[i];
}

// causal depthwise conv1d k=4, left pad 3. X:(B,L,D) fp32 -> XC:(B,L,D) bf16
__global__ __launch_bounds__(256) void conv_kernel(const float* __restrict__ X,
                                                   const float* __restrict__ cw,
                                                   const float* __restrict__ cb,
                                                   __bf16* __restrict__ XC) {
    int idx = blockIdx.x * 256 + threadIdx.x;
    int d = (idx & (DDIM / 4 - 1)) << 2;
    int t = (idx >> 8) & (LDIM - 1);
    int b = idx >> 19;
    float wv[4][4];
    *(float4*)wv[0] = ((const float4*)cw)[d + 0];
    *(float4*)wv[1] = ((const float4*)cw)[d + 1];
    *(float4*)wv[2] = ((const float4*)cw)[d + 2];
    *(float4*)wv[3] = ((const float4*)cw)[d + 3];
    float4 cbv = *(const float4*)(cb + d);
    float acc[4] = {cbv.x, cbv.y, cbv.z, cbv.w};
#pragma unroll
    for (int k = 0; k < K4; k++) {
        int tt = t + k - (K4 - 1);
        if (tt >= 0) {
            float4 xv = *(const float4*)(X + ((size_t)(b * LDIM + tt) << 10) + d);
            acc[0] += xv.x * wv[0][k];
            acc[1] += xv.y * wv[1][k];
            acc[2] += xv.z * wv[2][k];
            acc[3] += xv.w * wv[3][k];
        }
    }
    bf16x4 o;
    o.x = (__bf16)acc[0]; o.y = (__bf16)acc[1]; o.z = (__bf16)acc[2]; o.w = (__bf16)acc[3];
    *(bf16x4*)(XC + ((size_t)(b * LDIM + t) << 10) + d) = o;
}

// Dual GEMM (bf16, global_load_lds staging): r = A@Wr^T+wrb, i = A@Wi^T+wib
// epilogue -> LOGA, BB (bf16)
__global__ __launch_bounds__(256) void dual_gemm_gate(
    const __bf16* __restrict__ A, const __bf16* __restrict__ Wr, const __bf16* __restrict__ Wi,
    const float* __restrict__ wrb, const float* __restrict__ wib, const float* __restrict__ la,
    __bf16* __restrict__ LOGA, __bf16* __restrict__ BB) {
    __shared__ __bf16 sm[3 * 4096];
    __bf16* As = sm;
    __bf16* Rs = sm + 4096;
    __bf16* Is = sm + 8192;
    int tid = threadIdx.x;
    int bm0 = blockIdx.y * 128, bn0 = blockIdx.x * 128;
    int wave = tid >> 6, lane = tid & 63;
    int wm = (wave >> 1) * 64, wn = (wave & 1) * 64;
    int fr = lane & 15, quad = lane >> 4;
    f32x4 accr[4][4], acci[4][4];
    f32x4 zero = {0.f, 0.f, 0.f, 0.f};
#pragma unroll
    for (int i = 0; i < 4; i++)
#pragma unroll
        for (int j = 0; j < 4; j++) { accr[i][j] = zero; acci[i][j] = zero; }

    for (int ko = 0; ko < DDIM; ko += 32) {
        if (ko) __syncthreads();
#pragma unroll
        for (int j = 0; j < 2; j++) {
            int ck = j * 4 + wave;            // chunk 0..7, wave-uniform
            int ci = ck * 64 + lane;          // per-lane element group
            int r = ci >> 2, kc = (ci & 3) << 3;
            size_t go = (size_t)r * DDIM + ko + kc;
            // wave-uniform LDS base: chunk ck occupies elements [ck*512, ck*512+512)
            load16(A + (size_t)bm0 * DDIM + go, As + ck * 512);
            load16(Wr + (size_t)bn0 * DDIM + go, Rs + ck * 512);
            load16(Wi + (size_t)bn0 * DDIM + go, Is + ck * 512);
        }
        __syncthreads();
        bf16x8 af[4];
#pragma unroll
        for (int mi = 0; mi < 4; mi++)
            af[mi] = *(const bf16x8*)(As + (wm + mi * 16 + fr) * 32 + quad * 8);
#pragma unroll
        for (int ni = 0; ni < 4; ni++) {
            bf16x8 br = *(const bf16x8*)(Rs + (wn + ni * 16 + fr) * 32 + quad * 8);
            bf16x8 bi = *(const bf16x8*)(Is + (wn + ni * 16 + fr) * 32 + quad * 8);
#pragma unroll
            for (int mi = 0; mi < 4; mi++) {
                accr[mi][ni] = __builtin_amdgcn_mfma_f32_16x16x32_bf16(af[mi], br, accr[mi][ni], 0, 0, 0);
                acci[mi][ni] = __builtin_amdgcn_mfma_f32_16x16x32_bf16(af[mi], bi, acci[mi][ni], 0, 0, 0);
            }
        }
    }
#pragma unroll
    for (int ni = 0; ni < 4; ni++) {
        int n = bn0 + wn + ni * 16 + fr;
        float lav = la[n];
        float ab = 1.f / (1.f + __expf(-lav));
        float lnab = __logf(ab);
        float br_ = wrb[n], bi_ = wib[n];
#pragma unroll
        for (int mi = 0; mi < 4; mi++) {
#pragma unroll
            for (int reg = 0; reg < 4; reg++) {
                int m = bm0 + wm + mi * 16 + quad * 4 + reg;
                float rl = accr[mi][ni][reg] + br_;
                float il = acci[mi][ni][reg] + bi_;
                float r = 1.f / (1.f + __expf(-rl));
                float iv = 1.f / (1.f + __expf(-il));
                float lga = 8.f * r * lnab;
                float a = __expf(lga);
                float xc = (float)A[(size_t)m * DDIM + n];
                float bt = sqrtf(fmaxf(1.f - a * a, 1e-6f)) * (iv * xc);
                size_t off = (size_t)m * DDIM + n;
                LOGA[off] = (__bf16)lga;
                BB[off] = (__bf16)bt;
            }
        }
    }
}

// HW = A @ Wo^T  (A bf16 MxK, Wo bf16 NxK, HW fp32)
__global__ __launch_bounds__(256) void out_gemm(
    const __bf16* __restrict__ A, const __bf16* __restrict__ Wo, float* __restrict__ HW) {
    __shared__ __bf16 sm[2 * 4096];
    __bf16* As = sm;
    __bf16* Bs = sm + 4096;
    int tid = threadIdx.x;
    int bm0 = blockIdx.y * 128, bn0 = blockIdx.x * 128;
    int wave = tid >> 6, lane = tid & 63;
    int wm = (wave >> 1) * 64, wn = (wave & 1) * 64;
    int fr = lane & 15, quad = lane >> 4;
    f32x4 acc[4][4];
    f32x4 zero = {0.f, 0.f, 0.f, 0.f};
#pragma unroll
    for (int i = 0; i < 4; i++)
#pragma unroll
        for (int j = 0; j < 4; j++) acc[i][j] = zero;

    for (int ko = 0; ko < DDIM; ko += 32) {
        if (ko) __syncthreads();
#pragma unroll
        for (int j = 0; j < 2; j++) {
            int ck = j * 4 + wave;
            int ci = ck * 64 + lane;
            int r = ci >> 2, kc = (ci & 3) << 3;
            size_t go = (size_t)r * DDIM + ko + kc;
            load16(A + (size_t)bm0 * DDIM + go, As + ck * 512);
            load16(Wo + (size_t)bn0 * DDIM + go, Bs + ck * 512);
        }
        __syncthreads();
        bf16x8 af[4];
#pragma unroll
        for (int mi = 0; mi < 4; mi++)
            af[mi] = *(const bf16x8*)(As + (wm + mi * 16 + fr) * 32 + quad * 8);
#pragma unroll
        for (int ni = 0; ni < 4; ni++) {
            bf16x8 bb = *(const bf16x8*)(Bs + (wn + ni * 16 + fr) * 32 + quad * 8);
#pragma unroll
            for (int mi = 0; mi < 4; mi++)
                acc[mi][ni] = __builtin_amdgcn_mfma_f32_16x16x32_bf16(af[mi], bb, acc[mi][ni], 0, 0, 0);
        }
    }
#pragma unroll
    for (int ni = 0; ni < 4; ni++) {
        int n = bn0 + wn + ni * 16 + fr;
#pragma unroll
        for (int mi = 0; mi < 4; mi++) {
#pragma unroll
            for (int reg = 0; reg < 4; reg++) {
                int m = bm0 + wm + mi * 16 + quad * 4 + reg;
                HW[(size_t)m * DDIM + n] = acc[mi][ni][reg];
            }
        }
    }
}

// Clamped log-space scan (reference-equivalent telescoped recurrence), bf16 IO, fp32 math.
// block: 256 thr = 32 d-lanes x 8 t-chunks of 256. grid: (D/32, B) = 256 blocks.
#define SC_T (LDIM / 8) /* 256 */
__global__ __launch_bounds__(256) void scan_kernel(const __bf16* __restrict__ LOGA,
                                                   const __bf16* __restrict__ BB,
                                                   __bf16* __restrict__ H) {
    int b = blockIdx.y;
    int dl = threadIdx.x & 31;
    int d = blockIdx.x * 32 + dl;
    int c = threadIdx.x >> 5;
    size_t base = ((size_t)b * LDIM + (size_t)c * SC_T) * DDIM + d;
    const __bf16* pga = LOGA + base;
    const __bf16* pbb = BB + base;
    __bf16* pH = H + base;

    // phase A: chunk sums of loga
    float S = 0.f;
#pragma unroll 8
    for (int t = 0; t < SC_T; t++) S += (float)pga[(size_t)t * DDIM];
    __shared__ float sS[8][32];
    sS[c][dl] = S;
    __syncthreads();
    float L0 = 0.f;
    for (int cc = 0; cc < c; cc++) L0 += sS[cc][dl];

    // phase B: chunk (A_c, B_c) with zero initial state
    float Lr = L0, lcp = fmaxf(L0, -80.f), hB = 0.f;
#pragma unroll 4
    for (int t = 0; t < SC_T; t++) {
        float lga = (float)pga[(size_t)t * DDIM];
        Lr += lga;
        float lc = fmaxf(Lr, -80.f);
        hB = __expf(lc - lcp) * hB + (float)pbb[(size_t)t * DDIM];
        lcp = lc;
    }
    float Ac = __expf(fmaxf(Lr, -80.f) - fmaxf(L0, -80.f));
    __shared__ float sA[8][32], sB[8][32];
    sA[c][dl] = Ac;
    sB[c][dl] = hB;
    __syncthreads();
    float hin = 0.f;
    for (int cc = 0; cc < c; cc++) hin = sA[cc][dl] * hin + sB[cc][dl];

    // phase C: replay with real h_in, write h (bf16)
    Lr = L0;
    lcp = fmaxf(L0, -80.f);
    float h = hin;
#pragma unroll 4
    for (int t = 0; t < SC_T; t++) {
        float lga = (float)pga[(size_t)t * DDIM];
        Lr += lga;
        float lc = fmaxf(Lr, -80.f);
        h = __expf(lc - lcp) * h + (float)pbb[(size_t)t * DDIM];
        lcp = lc;
        pH[(size_t)t * DDIM] = (__bf16)h;
    }
}

// rmsnorm over last dim (1024); one block per row, 256 threads x float4. fp32 -> fp32
__global__ __launch_bounds__(256) void rmsnorm_kernel(const float* __restrict__ X,
                                                      const float* __restrict__ w,
                                                      float* __restrict__ Y) {
    int row = blockIdx.x;
    int tid = threadIdx.x;
    const float4* px = (const float4*)(X + (size_t)row * DDIM);
    float4 v = px[tid];
    float s = v.x * v.x + v.y * v.y + v.z * v.z + v.w * v.w;
#pragma unroll
    for (int o = 32; o > 0; o >>= 1) s += __shfl_down(s, o);
    __shared__ float sw[4];
    if ((tid & 63) == 0) sw[tid >> 6] = s;
    __syncthreads();
    float tot = sw[0] + sw[1] + sw[2] + sw[3];
    float scale = rsqrtf(tot * (1.f / (float)DDIM) + 1e-6f);
    float4 wv = ((const float4*)w)[tid];
    float4 o;
    o.x = v.x * wv.x * scale;
    o.y = v.y * wv.y * scale;
    o.z = v.z * wv.z * scale;
    o.w = v.w * wv.w * scale;
    ((float4*)(Y + (size_t)row * DDIM))[tid] = o;
}

extern "C" void kernel_launch(void* const* d_in, const int* in_sizes, int n_in,
                              void* d_out, int out_size, void* d_ws, size_t ws_size,
                              hipStream_t stream) {
    const float* x = (const float*)d_in[0];
    const float* conv_w = (const float*)d_in[1];
    const float* conv_b = (const float*)d_in[2];
    const float* wr_w = (const float*)d_in[3];
    const float* wr_b = (const float*)d_in[4];
    const float* wi_w = (const float*)d_in[5];
    const float* wi_b = (const float*)d_in[6];
    const float* log_a = (const float*)d_in[7];
    const float* wo_w = (const float*)d_in[8];
    const float* norm_w = (const float*)d_in[9];
    const float* norm_out_w = (const float*)d_in[10];

    const size_t WSZ = (size_t)NL * DDIM * DDIM; // 3.1M elems per weight tensor
    const size_t MD = (size_t)MDIM * DDIM;       // 16.7M activations
    // Workspace plan (total ~220 MB, same footprint as the R1 run that passed):
    //   wr16|wi16|wo16 (bf16, 6.3MB ea) | XC (bf16 33.5MB) | LGA (bf16 33.5MB)
    //   | BBf (bf16 33.5MB) | Hb (bf16 33.5MB) | HW (fp32 67MB)
    // PN (fp32 67MB) ALIASES [LGA,BBf] — dead after scan, rewritten only after
    // conv has consumed PN next layer.
    __bf16* wr16 = (__bf16*)d_ws;
    __bf16* wi16 = wr16 + WSZ;
    __bf16* wo16 = wi16 + WSZ;
    __bf16* XC = wo16 + WSZ;
    __bf16* LGA = XC + MD;
    __bf16* BBf = LGA + MD;
    __bf16* Hb = BBf + MD;
    float* HW = (float*)(Hb + MD);
    float* PN = (float*)LGA; // alias: LGA+BBf region (67 MB) == PN (67 MB)

    int ncvt = (int)WSZ;
    cvt_bf16<<<(ncvt + 255) / 256, 256, 0, stream>>>(wr_w, wr16, ncvt);
    cvt_bf16<<<(ncvt + 255) / 256, 256, 0, stream>>>(wi_w, wi16, ncvt);
    cvt_bf16<<<(ncvt + 255) / 256, 256, 0, stream>>>(wo_w, wo16, ncvt);

    const float* P = x;
    for (int l = 0; l < NL; l++) {
        conv_kernel<<<(MDIM * (DDIM / 4)) / 256, 256, 0, stream>>>(
            P, conv_w + (size_t)l * DDIM * K4, conv_b + (size_t)l * DDIM, XC);
        dual_gemm_gate<<<dim3(DDIM / 128, MDIM / 128), 256, 0, stream>>>(
            XC, wr16 + (size_t)l * DDIM * DDIM, wi16 + (size_t)l * DDIM * DDIM,
            wr_b + (size_t)l * DDIM, wi_b + (size_t)l * DDIM, log_a + (size_t)l * DDIM,
            LGA, BBf);
        scan_kernel<<<dim3(DDIM / 32, BDIM), 256, 0, stream>>>(LGA, BBf, Hb);
        out_gemm<<<dim3(DDIM / 128, MDIM / 128), 256, 0, stream>>>(
            Hb, wo16 + (size_t)l * DDIM * DDIM, HW);
        rmsnorm_kernel<<<MDIM, 256, 0, stream>>>(HW, norm_w + (size_t)l * DDIM, PN);
        P = PN;
    }
    rmsnorm_kernel<<<MDIM, 256, 0, stream>>>(PN, norm_out_w, (float*)d_out);
}

// Round 4
// 1187.234 us; speedup vs baseline: 1.9204x; 1.1298x over previous
//
#include <hip/hip_runtime.h>
#include <type_traits>

#define BDIM 8
#define LDIM 2048
#define DDIM 1024
#define NL 3
#define K4 4
#define MDIM (BDIM * LDIM) /* 16384 rows */

typedef __bf16 bf16x8 __attribute__((ext_vector_type(8)));
typedef __bf16 bf16x4 __attribute__((ext_vector_type(4)));
typedef float f32x4 __attribute__((ext_vector_type(4)));
typedef const __attribute__((address_space(1))) void gvoid_t;
typedef __attribute__((address_space(3))) void svoid_t;

// wave-uniform LDS base; lane l's 16B lands at base + l*16 (m104/m108).
__device__ __forceinline__ void load16(const void* g, void* lds_uniform) {
    __builtin_amdgcn_global_load_lds((gvoid_t*)g, (svoid_t*)lds_uniform, 16, 0, 0);
}

__global__ void cvt_bf16(const float* __restrict__ s, __bf16* __restrict__ d, int n) {
    int i = blockIdx.x * 256 + threadIdx.x;
    if (i < n) d[i] = (__bf16)s[i];
}

// causal depthwise conv1d k=4, left pad 3. X:(B,L,D) -> XC:(B,L,D) bf16
template <typename T>
__global__ __launch_bounds__(256) void conv_kernel(const T* __restrict__ X,
                                                   const float* __restrict__ cw,
                                                   const float* __restrict__ cb,
                                                   __bf16* __restrict__ XC) {
    int idx = blockIdx.x * 256 + threadIdx.x;
    int d = (idx & (DDIM / 4 - 1)) << 2;
    int t = (idx >> 8) & (LDIM - 1);
    int b = idx >> 19;
    float wv[4][4];
    *(float4*)wv[0] = ((const float4*)cw)[d + 0];
    *(float4*)wv[1] = ((const float4*)cw)[d + 1];
    *(float4*)wv[2] = ((const float4*)cw)[d + 2];
    *(float4*)wv[3] = ((const float4*)cw)[d + 3];
    float4 cbv = *(const float4*)(cb + d);
    float acc[4] = {cbv.x, cbv.y, cbv.z, cbv.w};
#pragma unroll
    for (int k = 0; k < K4; k++) {
        int tt = t + k - (K4 - 1);
        if (tt >= 0) {
            size_t off = ((size_t)(b * LDIM + tt) << 10) + d;
            float xv[4];
            if constexpr (std::is_same<T, float>::value) {
                float4 v = *(const float4*)(X + off);
                xv[0] = v.x; xv[1] = v.y; xv[2] = v.z; xv[3] = v.w;
            } else {
                bf16x4 v = *(const bf16x4*)(X + off);
                xv[0] = (float)v.x; xv[1] = (float)v.y; xv[2] = (float)v.z; xv[3] = (float)v.w;
            }
#pragma unroll
            for (int j = 0; j < 4; j++) acc[j] += xv[j] * wv[j][k];
        }
    }
    bf16x4 o;
    o.x = (__bf16)acc[0]; o.y = (__bf16)acc[1]; o.z = (__bf16)acc[2]; o.w = (__bf16)acc[3];
    *(bf16x4*)(XC + ((size_t)(b * LDIM + t) << 10) + d) = o;
}

// ---- swizzled LDS helpers (BK=64): slot(r, sc) holds global chunk sc^(r&7).
// bank = (swz*4 + word) mod 32 -> 2-way max (free).

// Dual GEMM + gate epilogue (bf16). BK=64, XOR swizzle, LDS-transposed epilogue.
__global__ __launch_bounds__(256) void dual_gemm_gate(
    const __bf16* __restrict__ A, const __bf16* __restrict__ Wr, const __bf16* __restrict__ Wi,
    const float* __restrict__ wrb, const float* __restrict__ wib, const float* __restrict__ la,
    __bf16* __restrict__ LOGA, __bf16* __restrict__ BB) {
    __shared__ __attribute__((aligned(16))) char smraw[49152]; // 48 KB
    __bf16* As = (__bf16*)smraw;
    __bf16* Rs = As + 8192;
    __bf16* Is = As + 16384;
    int tid = threadIdx.x;
    int bm0 = blockIdx.y * 128, bn0 = blockIdx.x * 128;
    int wave = tid >> 6, lane = tid & 63;
    int wm = (wave >> 1) * 64, wn = (wave & 1) * 64;
    int fr = lane & 15, quad = lane >> 4;
    f32x4 accr[4][4], acci[4][4];
    f32x4 zero = {0.f, 0.f, 0.f, 0.f};
#pragma unroll
    for (int i = 0; i < 4; i++)
#pragma unroll
        for (int j = 0; j < 4; j++) { accr[i][j] = zero; acci[i][j] = zero; }

    for (int ko = 0; ko < DDIM; ko += 64) {
        if (ko) __syncthreads();
#pragma unroll
        for (int j = 0; j < 4; j++) {
            int ci = (j * 4 + wave) * 64 + lane;   // 0..1023
            int r = ci >> 3, sc = ci & 7;
            int g = sc ^ (r & 7);                  // swizzled source chunk
            size_t go = (size_t)r * DDIM + ko + g * 8;
            int lb = (j * 4 + wave) * 512;         // wave-uniform base (elements)
            load16(A + (size_t)bm0 * DDIM + go, As + lb);
            load16(Wr + (size_t)bn0 * DDIM + go, Rs + lb);
            load16(Wi + (size_t)bn0 * DDIM + go, Is + lb);
        }
        __syncthreads();
#pragma unroll
        for (int kw8 = 0; kw8 < 8; kw8 += 4) { // two 32-wide MFMA windows
            bf16x8 af[4];
#pragma unroll
            for (int mi = 0; mi < 4; mi++) {
                int row = wm + mi * 16 + fr;
                af[mi] = *(const bf16x8*)(As + row * 64 + ((kw8 + quad) ^ (row & 7)) * 8);
            }
#pragma unroll
            for (int ni = 0; ni < 4; ni++) {
                int row = wn + ni * 16 + fr;
                int so = row * 64 + ((kw8 + quad) ^ (row & 7)) * 8;
                bf16x8 br = *(const bf16x8*)(Rs + so);
                bf16x8 bi = *(const bf16x8*)(Is + so);
#pragma unroll
                for (int mi = 0; mi < 4; mi++) {
                    accr[mi][ni] = __builtin_amdgcn_mfma_f32_16x16x32_bf16(af[mi], br, accr[mi][ni], 0, 0, 0);
                    acci[mi][ni] = __builtin_amdgcn_mfma_f32_16x16x32_bf16(af[mi], bi, acci[mi][ni], 0, 0, 0);
                }
            }
        }
    }

    // ---- epilogue: LDS transpose -> coalesced gate math ----
    float* Ltr = (float*)smraw;            // [32][132] f32
    float* Lti = Ltr + 32 * 132;
    int wrow = (wave >> 1) * 16, wcol = (wave & 1) * 64;
    int colg = (tid & 15) * 8;             // this thread's 8-col group
    int n0 = bn0 + colg;
    // hoist per-column params
    float lnab8[8], rb8[8], ib8[8];
    {
        float4 l0 = *(const float4*)(la + n0), l1 = *(const float4*)(la + n0 + 4);
        float4 r0 = *(const float4*)(wrb + n0), r1 = *(const float4*)(wrb + n0 + 4);
        float4 i0 = *(const float4*)(wib + n0), i1 = *(const float4*)(wib + n0 + 4);
        float lav[8] = {l0.x, l0.y, l0.z, l0.w, l1.x, l1.y, l1.z, l1.w};
        float rbv[8] = {r0.x, r0.y, r0.z, r0.w, r1.x, r1.y, r1.z, r1.w};
        float ibv[8] = {i0.x, i0.y, i0.z, i0.w, i1.x, i1.y, i1.z, i1.w};
#pragma unroll
        for (int j = 0; j < 8; j++) {
            lnab8[j] = __logf(1.f / (1.f + __expf(-lav[j])));
            rb8[j] = rbv[j]; ib8[j] = ibv[j];
        }
    }
#pragma unroll
    for (int mi = 0; mi < 4; mi++) {
        __syncthreads();
#pragma unroll
        for (int ni = 0; ni < 4; ni++) {
            int col = wcol + ni * 16 + fr;
#pragma unroll
            for (int reg = 0; reg < 4; reg++) {
                int lrow = wrow + quad * 4 + reg;
                Ltr[lrow * 132 + col] = accr[mi][ni][reg];
                Lti[lrow * 132 + col] = acci[mi][ni][reg];
            }
        }
        __syncthreads();
#pragma unroll
        for (int half = 0; half < 2; half++) {
            int lrow = (tid >> 4) + half * 16;
            int m = bm0 + (lrow >> 4) * 64 + mi * 16 + (lrow & 15);
            float rr[8], ii[8];
            *(f32x4*)&rr[0] = *(const f32x4*)&Ltr[lrow * 132 + colg];
            *(f32x4*)&rr[4] = *(const f32x4*)&Ltr[lrow * 132 + colg + 4];
            *(f32x4*)&ii[0] = *(const f32x4*)&Lti[lrow * 132 + colg];
            *(f32x4*)&ii[4] = *(const f32x4*)&Lti[lrow * 132 + colg + 4];
            bf16x8 xcv = *(const bf16x8*)(A + (size_t)m * DDIM + n0);
            bf16x8 og, ob;
#pragma unroll
            for (int j = 0; j < 8; j++) {
                float r = 1.f / (1.f + __expf(-(rr[j] + rb8[j])));
                float iv = 1.f / (1.f + __expf(-(ii[j] + ib8[j])));
                float lga = 8.f * r * lnab8[j];
                float a = __expf(lga);
                float bt = sqrtf(fmaxf(1.f - a * a, 1e-6f)) * (iv * (float)xcv[j]);
                og[j] = (__bf16)lga;
                ob[j] = (__bf16)bt;
            }
            *(bf16x8*)(LOGA + (size_t)m * DDIM + n0) = og;
            *(bf16x8*)(BB + (size_t)m * DDIM + n0) = ob;
        }
    }
}

// HW = A @ Wo^T  (bf16 in, bf16 out). BK=64, swizzled, transposed epilogue.
__global__ __launch_bounds__(256) void out_gemm(
    const __bf16* __restrict__ A, const __bf16* __restrict__ Wo, __bf16* __restrict__ HW) {
    __shared__ __attribute__((aligned(16))) char smraw[32768]; // 32 KB
    __bf16* As = (__bf16*)smraw;
    __bf16* Bs = As + 8192;
    int tid = threadIdx.x;
    int bm0 = blockIdx.y * 128, bn0 = blockIdx.x * 128;
    int wave = tid >> 6, lane = tid & 63;
    int wm = (wave >> 1) * 64, wn = (wave & 1) * 64;
    int fr = lane & 15, quad = lane >> 4;
    f32x4 acc[4][4];
    f32x4 zero = {0.f, 0.f, 0.f, 0.f};
#pragma unroll
    for (int i = 0; i < 4; i++)
#pragma unroll
        for (int j = 0; j < 4; j++) acc[i][j] = zero;

    for (int ko = 0; ko < DDIM; ko += 64) {
        if (ko) __syncthreads();
#pragma unroll
        for (int j = 0; j < 4; j++) {
            int ci = (j * 4 + wave) * 64 + lane;
            int r = ci >> 3, sc = ci & 7;
            int g = sc ^ (r & 7);
            size_t go = (size_t)r * DDIM + ko + g * 8;
            int lb = (j * 4 + wave) * 512;
            load16(A + (size_t)bm0 * DDIM + go, As + lb);
            load16(Wo + (size_t)bn0 * DDIM + go, Bs + lb);
        }
        __syncthreads();
#pragma unroll
        for (int kw8 = 0; kw8 < 8; kw8 += 4) {
            bf16x8 af[4];
#pragma unroll
            for (int mi = 0; mi < 4; mi++) {
                int row = wm + mi * 16 + fr;
                af[mi] = *(const bf16x8*)(As + row * 64 + ((kw8 + quad) ^ (row & 7)) * 8);
            }
#pragma unroll
            for (int ni = 0; ni < 4; ni++) {
                int row = wn + ni * 16 + fr;
                bf16x8 bb = *(const bf16x8*)(Bs + row * 64 + ((kw8 + quad) ^ (row & 7)) * 8);
#pragma unroll
                for (int mi = 0; mi < 4; mi++)
                    acc[mi][ni] = __builtin_amdgcn_mfma_f32_16x16x32_bf16(af[mi], bb, acc[mi][ni], 0, 0, 0);
            }
        }
    }
    // transposed epilogue -> coalesced bf16 stores
    float* Lt = (float*)smraw; // [32][132]
    int wrow = (wave >> 1) * 16, wcol = (wave & 1) * 64;
    int colg = (tid & 15) * 8;
    int n0 = bn0 + colg;
#pragma unroll
    for (int mi = 0; mi < 4; mi++) {
        __syncthreads();
#pragma unroll
        for (int ni = 0; ni < 4; ni++) {
            int col = wcol + ni * 16 + fr;
#pragma unroll
            for (int reg = 0; reg < 4; reg++) {
                int lrow = wrow + quad * 4 + reg;
                Lt[lrow * 132 + col] = acc[mi][ni][reg];
            }
        }
        __syncthreads();
#pragma unroll
        for (int half = 0; half < 2; half++) {
            int lrow = (tid >> 4) + half * 16;
            int m = bm0 + (lrow >> 4) * 64 + mi * 16 + (lrow & 15);
            float vv[8];
            *(f32x4*)&vv[0] = *(const f32x4*)&Lt[lrow * 132 + colg];
            *(f32x4*)&vv[4] = *(const f32x4*)&Lt[lrow * 132 + colg + 4];
            bf16x8 o;
#pragma unroll
            for (int j = 0; j < 8; j++) o[j] = (__bf16)vv[j];
            *(bf16x8*)(HW + (size_t)m * DDIM + n0) = o;
        }
    }
}

// Clamped log-space scan (reference-equivalent telescoped recurrence), bf16 IO, fp32 math.
#define SC_T (LDIM / 8) /* 256 */
__global__ __launch_bounds__(256) void scan_kernel(const __bf16* __restrict__ LOGA,
                                                   const __bf16* __restrict__ BB,
                                                   __bf16* __restrict__ H) {
    int b = blockIdx.y;
    int dl = threadIdx.x & 31;
    int d = blockIdx.x * 32 + dl;
    int c = threadIdx.x >> 5;
    size_t base = ((size_t)b * LDIM + (size_t)c * SC_T) * DDIM + d;
    const __bf16* pga = LOGA + base;
    const __bf16* pbb = BB + base;
    __bf16* pH = H + base;

    float S = 0.f;
#pragma unroll 8
    for (int t = 0; t < SC_T; t++) S += (float)pga[(size_t)t * DDIM];
    __shared__ float sS[8][32];
    sS[c][dl] = S;
    __syncthreads();
    float L0 = 0.f;
    for (int cc = 0; cc < c; cc++) L0 += sS[cc][dl];

    float Lr = L0, lcp = fmaxf(L0, -80.f), hB = 0.f;
#pragma unroll 4
    for (int t = 0; t < SC_T; t++) {
        float lga = (float)pga[(size_t)t * DDIM];
        Lr += lga;
        float lc = fmaxf(Lr, -80.f);
        hB = __expf(lc - lcp) * hB + (float)pbb[(size_t)t * DDIM];
        lcp = lc;
    }
    float Ac = __expf(fmaxf(Lr, -80.f) - fmaxf(L0, -80.f));
    __shared__ float sA[8][32], sB[8][32];
    sA[c][dl] = Ac;
    sB[c][dl] = hB;
    __syncthreads();
    float hin = 0.f;
    for (int cc = 0; cc < c; cc++) hin = sA[cc][dl] * hin + sB[cc][dl];

    Lr = L0;
    lcp = fmaxf(L0, -80.f);
    float h = hin;
#pragma unroll 4
    for (int t = 0; t < SC_T; t++) {
        float lga = (float)pga[(size_t)t * DDIM];
        Lr += lga;
        float lc = fmaxf(Lr, -80.f);
        h = __expf(lc - lcp) * h + (float)pbb[(size_t)t * DDIM];
        lcp = lc;
        pH[(size_t)t * DDIM] = (__bf16)h;
    }
}

// rmsnorm over last dim (1024); one block per row, 256 threads x 4 elems.
template <typename TI, typename TO>
__global__ __launch_bounds__(256) void rmsnorm_kernel(const TI* __restrict__ X,
                                                      const float* __restrict__ w,
                                                      TO* __restrict__ Y) {
    int row = blockIdx.x;
    int tid = threadIdx.x;
    size_t off = (size_t)row * DDIM + tid * 4;
    float v[4];
    if constexpr (std::is_same<TI, float>::value) {
        float4 t = *(const float4*)(X + off);
        v[0] = t.x; v[1] = t.y; v[2] = t.z; v[3] = t.w;
    } else {
        bf16x4 t = *(const bf16x4*)(X + off);
        v[0] = (float)t.x; v[1] = (float)t.y; v[2] = (float)t.z; v[3] = (float)t.w;
    }
    float s = v[0] * v[0] + v[1] * v[1] + v[2] * v[2] + v[3] * v[3];
#pragma unroll
    for (int o = 32; o > 0; o >>= 1) s += __shfl_down(s, o);
    __shared__ float sw[4];
    if ((tid & 63) == 0) sw[tid >> 6] = s;
    __syncthreads();
    float tot = sw[0] + sw[1] + sw[2] + sw[3];
    float scale = rsqrtf(tot * (1.f / (float)DDIM) + 1e-6f);
    float4 wv = ((const float4*)w)[tid];
    float o0 = v[0] * wv.x * scale, o1 = v[1] * wv.y * scale;
    float o2 = v[2] * wv.z * scale, o3 = v[3] * wv.w * scale;
    if constexpr (std::is_same<TO, float>::value) {
        float4 o = {o0, o1, o2, o3};
        *(float4*)(Y + off) = o;
    } else {
        bf16x4 o;
        o.x = (__bf16)o0; o.y = (__bf16)o1; o.z = (__bf16)o2; o.w = (__bf16)o3;
        *(bf16x4*)(Y + off) = o;
    }
}

extern "C" void kernel_launch(void* const* d_in, const int* in_sizes, int n_in,
                              void* d_out, int out_size, void* d_ws, size_t ws_size,
                              hipStream_t stream) {
    const float* x = (const float*)d_in[0];
    const float* conv_w = (const float*)d_in[1];
    const float* conv_b = (const float*)d_in[2];
    const float* wr_w = (const float*)d_in[3];
    const float* wr_b = (const float*)d_in[4];
    const float* wi_w = (const float*)d_in[5];
    const float* wi_b = (const float*)d_in[6];
    const float* log_a = (const float*)d_in[7];
    const float* wo_w = (const float*)d_in[8];
    const float* norm_w = (const float*)d_in[9];
    const float* norm_out_w = (const float*)d_in[10];

    const size_t WSZ = (size_t)NL * DDIM * DDIM;
    const size_t MD = (size_t)MDIM * DDIM;
    // ws: 3 bf16 weights (18.9 MB) + 6 bf16 activation bufs (33.5 MB ea) = 220 MB
    __bf16* wr16 = (__bf16*)d_ws;
    __bf16* wi16 = wr16 + WSZ;
    __bf16* wo16 = wi16 + WSZ;
    __bf16* XC = wo16 + WSZ;
    __bf16* LGA = XC + MD;
    __bf16* BBf = LGA + MD;
    __bf16* Hb = BBf + MD;
    __bf16* HWb = Hb + MD;
    __bf16* PNb = HWb + MD;

    int ncvt = (int)WSZ;
    cvt_bf16<<<(ncvt + 255) / 256, 256, 0, stream>>>(wr_w, wr16, ncvt);
    cvt_bf16<<<(ncvt + 255) / 256, 256, 0, stream>>>(wi_w, wi16, ncvt);
    cvt_bf16<<<(ncvt + 255) / 256, 256, 0, stream>>>(wo_w, wo16, ncvt);

    for (int l = 0; l < NL; l++) {
        if (l == 0)
            conv_kernel<float><<<(MDIM * (DDIM / 4)) / 256, 256, 0, stream>>>(
                x, conv_w, conv_b, XC);
        else
            conv_kernel<__bf16><<<(MDIM * (DDIM / 4)) / 256, 256, 0, stream>>>(
                PNb, conv_w + (size_t)l * DDIM * K4, conv_b + (size_t)l * DDIM, XC);
        dual_gemm_gate<<<dim3(DDIM / 128, MDIM / 128), 256, 0, stream>>>(
            XC, wr16 + (size_t)l * DDIM * DDIM, wi16 + (size_t)l * DDIM * DDIM,
            wr_b + (size_t)l * DDIM, wi_b + (size_t)l * DDIM, log_a + (size_t)l * DDIM,
            LGA, BBf);
        scan_kernel<<<dim3(DDIM / 32, BDIM), 256, 0, stream>>>(LGA, BBf, Hb);
        out_gemm<<<dim3(DDIM / 128, MDIM / 128), 256, 0, stream>>>(
            Hb, wo16 + (size_t)l * DDIM * DDIM, HWb);
        if (l < NL - 1)
            rmsnorm_kernel<__bf16, __bf16><<<MDIM, 256, 0, stream>>>(
                HWb, norm_w + (size_t)l * DDIM, PNb);
        else
            rmsnorm_kernel<__bf16, __bf16><<<MDIM, 256, 0, stream>>>(
                HWb, norm_w + (size_t)l * DDIM, PNb);
    }
    rmsnorm_kernel<__bf16, float><<<MDIM, 256, 0, stream>>>(PNb, norm_out_w, (float*)d_out);
}